// Round 2
// baseline (118.600 us; speedup 1.0000x reference)
//
#include <hip/hip_runtime.h>
#include <stdint.h>

// Problem dims (fixed by reference)
#define BB   8
#define SS   2048
#define DIN  1024
#define DOUT 64

typedef __bf16 bf16_t;
typedef __bf16 bf16x8 __attribute__((ext_vector_type(8)));
typedef float  f32x4  __attribute__((ext_vector_type(4)));
typedef unsigned int u32x4 __attribute__((ext_vector_type(4)));

#define LOG2E 1.44269504088896f

// ---------------------------------------------------------------------------
// Kernel 0: pre-pack weights (1024x64 fp32) into bf16 MFMA B-fragment order.
// Layout: fw[proj][kk=0..31][nt=0..3][lane=0..63][j=0..7]
//   value = W[k][col],  k = kk*32 + (lane>>4)*8 + j,  col = nt*16 + (lane&15)
// Q weights (proj==2) are scaled by 1/sqrt(64) = 0.125 (exact in bf16).
// ---------------------------------------------------------------------------
__global__ void prep_weights(const float* __restrict__ Kw,
                             const float* __restrict__ Vw,
                             const float* __restrict__ Qw,
                             bf16_t* __restrict__ fw) {
    int proj = blockIdx.x >> 4;   // 0..2
    int seg  = blockIdx.x & 15;   // 0..15
    const float* W = (proj == 0) ? Kw : (proj == 1) ? Vw : Qw;
    float scale = (proj == 2) ? 0.125f : 1.0f;
    bf16_t* out = fw + proj * 65536;
    int base = seg * 4096;
#pragma unroll
    for (int i = 0; i < 16; ++i) {
        int idx  = base + i * 256 + threadIdx.x;
        int j    = idx & 7;
        int lane = (idx >> 3) & 63;
        int nt   = (idx >> 9) & 3;
        int kk   = idx >> 11;
        int k    = kk * 32 + (lane >> 4) * 8 + j;
        int col  = nt * 16 + (lane & 15);
        out[idx] = (bf16_t)(W[k * DOUT + col] * scale);
    }
}

// ---------------------------------------------------------------------------
// Kernel 1: projection GEMM  [16384,1024](fp32) x [1024,64](bf16) -> bf16
// Barrier-free main loop: B-fragments read directly from global (L2-hit,
// coalesced 1KB/wave), A read directly from global fp32 (contiguous 32B/lane).
// K split in half across wave pairs (waves 0-3: K[0,512), waves 4-7: rest);
// partial sums reduced through LDS once at the end.
// Block: 512 threads = 8 waves. Grid: (256, 3) -> 24 waves/CU.
// ---------------------------------------------------------------------------
__global__ __launch_bounds__(512) void proj_kernel(
    const float* __restrict__ Xk, const float* __restrict__ Xv,
    const float* __restrict__ Xq, const bf16_t* __restrict__ fw,
    bf16_t* __restrict__ outK, bf16_t* __restrict__ outV,
    bf16_t* __restrict__ outQ) {
    __shared__ float red[4][16][64];   // 16 KB: partial sums from waves 4-7

    int tid  = threadIdx.x;
    int lane = tid & 63;
    int w    = tid >> 6;    // 0..7
    int wm   = w & 3;       // row strip within block
    int kh   = w >> 2;      // K half

    int proj = blockIdx.y;
    const float* X  = (proj == 0) ? Xk : (proj == 1) ? Xv : Xq;
    bf16_t* out     = (proj == 0) ? outK : (proj == 1) ? outV : outQ;

    int row0 = blockIdx.x * 64 + wm * 16;
    const float* aptr = X + (size_t)(row0 + (lane & 15)) * DIN + kh * 512 + (lane >> 4) * 8;
    const bf16_t* bptr = fw + proj * 65536 + kh * 32768 + lane * 8;

    f32x4 acc[4];
#pragma unroll
    for (int nt = 0; nt < 4; ++nt) acc[nt] = (f32x4)(0.0f);

#pragma unroll 2
    for (int kk = 0; kk < 16; ++kk) {
        f32x4 a0 = *(const f32x4*)(aptr + kk * 32);
        f32x4 a1 = *(const f32x4*)(aptr + kk * 32 + 4);
        bf16x8 b0 = *(const bf16x8*)(bptr + (kk * 4 + 0) * 512);
        bf16x8 b1 = *(const bf16x8*)(bptr + (kk * 4 + 1) * 512);
        bf16x8 b2 = *(const bf16x8*)(bptr + (kk * 4 + 2) * 512);
        bf16x8 b3 = *(const bf16x8*)(bptr + (kk * 4 + 3) * 512);
        bf16x8 af;
        af[0] = (bf16_t)a0[0]; af[1] = (bf16_t)a0[1];
        af[2] = (bf16_t)a0[2]; af[3] = (bf16_t)a0[3];
        af[4] = (bf16_t)a1[0]; af[5] = (bf16_t)a1[1];
        af[6] = (bf16_t)a1[2]; af[7] = (bf16_t)a1[3];
        acc[0] = __builtin_amdgcn_mfma_f32_16x16x32_bf16(af, b0, acc[0], 0, 0, 0);
        acc[1] = __builtin_amdgcn_mfma_f32_16x16x32_bf16(af, b1, acc[1], 0, 0, 0);
        acc[2] = __builtin_amdgcn_mfma_f32_16x16x32_bf16(af, b2, acc[2], 0, 0, 0);
        acc[3] = __builtin_amdgcn_mfma_f32_16x16x32_bf16(af, b3, acc[3], 0, 0, 0);
    }

    // reduce K-halves: waves 4-7 dump partials, waves 0-3 add + store
    if (kh == 1) {
#pragma unroll
        for (int nt = 0; nt < 4; ++nt)
#pragma unroll
            for (int r = 0; r < 4; ++r)
                red[wm][(lane >> 4) * 4 + r][nt * 16 + (lane & 15)] = acc[nt][r];
    }
    __syncthreads();
    if (kh == 0) {
#pragma unroll
        for (int nt = 0; nt < 4; ++nt)
#pragma unroll
            for (int r = 0; r < 4; ++r) {
                int rr = (lane >> 4) * 4 + r;
                int cc = nt * 16 + (lane & 15);
                float v = acc[nt][r] + red[wm][rr][cc];
                out[(size_t)(row0 + rr) * DOUT + cc] = (bf16_t)v;
            }
    }
}

// ---------------------------------------------------------------------------
// Kernel 2: causal flash attention, bf16 MFMA, fp32 accum.
// Grid: (64 q-tiles of 32 rows, 8 batches) = 512 blocks (2/CU).
// Block: 256 thr = 4 waves. Waves 0-1 (group 0) process EVEN k-tiles, waves
// 2-3 (group 1) process ODD k-tiles of the SAME 32 q-rows; flash-combine at
// the end through LDS. Halves the per-block critical path.
// K LDS:  [key][d] with byte ^= (key&7)<<4 swizzle
// V LDS:  transposed [d][key], byte ^= (d&7)<<4
// P LDS:  per-wave [q][key], byte ^= (q&7)<<4
// ---------------------------------------------------------------------------
__global__ __launch_bounds__(256) void attn_kernel(
    const bf16_t* __restrict__ Kp, const bf16_t* __restrict__ Vp,
    const bf16_t* __restrict__ Qp, float* __restrict__ out) {
    __shared__ __align__(16) bf16_t Klds[2][64 * 64];   // 16 KB (per group)
    __shared__ __align__(16) bf16_t Vlds[2][64 * 64];   // 16 KB (transposed)
    __shared__ __align__(16) bf16_t Plds[4][16 * 64];   // 8 KB (per wave)

    int tid   = threadIdx.x;
    int lane  = tid & 63;
    int w     = tid >> 6;     // 0..3
    int g     = w >> 1;       // group: 0 = even k-tiles, 1 = odd
    int wq    = w & 1;        // 16-row strip within q-tile
    int gt    = tid & 127;    // thread id within group
    int qt    = blockIdx.x;   // 0..63 (32-row q-tiles)
    int batch = blockIdx.y;

    const bf16_t* Kb = Kp + (size_t)batch * SS * DOUT;
    const bf16_t* Vb = Vp + (size_t)batch * SS * DOUT;
    const bf16_t* Qb = Qp + (size_t)batch * SS * DOUT;

    // Q fragments (already scaled by 1/8)
    bf16x8 aq0, aq1;
    {
        int r = qt * 32 + wq * 16 + (lane & 15);
        const bf16_t* qp = Qb + (size_t)r * DOUT + (lane >> 4) * 8;
        aq0 = *(const bf16x8*)(qp);
        aq1 = *(const bf16x8*)(qp + 32);
    }

    float m[4], lsum[4];
    f32x4 acc[4];
#pragma unroll
    for (int r = 0; r < 4; ++r) { m[r] = -1e30f; lsum[r] = 0.0f; }
#pragma unroll
    for (int nt = 0; nt < 4; ++nt) acc[nt] = (f32x4)(0.0f);

    int dt     = qt >> 1;          // diagonal 64-key tile
    int ntl    = dt + 1;           // # k-tiles for this q-tile
    int imax   = (ntl + 1) >> 1;   // per-group iterations

    char* Kl = (char*)&Klds[g][0];
    char* Vl = (char*)&Vlds[g][0];

    for (int i = 0; i < imax; ++i) {
        int t = 2 * i + g;
        bool act = t < ntl;
        __syncthreads();
        if (act) {
            const bf16_t* Kt = Kb + (size_t)t * 64 * DOUT;
            const bf16_t* Vt = Vb + (size_t)t * 64 * DOUT;
#pragma unroll
            for (int ii = 0; ii < 4; ++ii) {
                int c   = gt + 128 * ii;       // 0..511
                int key = c >> 3;
                int d0  = (c & 7) * 8;
                u32x4 kv = *(const u32x4*)(Kt + (size_t)key * DOUT + d0);
                *(u32x4*)(Kl + key * 128 + ((d0 * 2) ^ ((key & 7) << 4))) = kv;
                bf16x8 vv = *(const bf16x8*)(Vt + (size_t)key * DOUT + d0);
#pragma unroll
                for (int jj = 0; jj < 8; ++jj) {
                    int d = d0 + jj;
                    *(bf16_t*)(Vl + d * 128 + ((key * 2) ^ ((d & 7) << 4))) = vv[jj];
                }
            }
        }
        __syncthreads();
        if (!act) continue;

        // ---- S = Q K^T ----
        f32x4 sfr[4];
#pragma unroll
        for (int nt = 0; nt < 4; ++nt) sfr[nt] = (f32x4)(0.0f);
#pragma unroll
        for (int kk = 0; kk < 2; ++kk) {
            int d0 = kk * 32 + (lane >> 4) * 8;
#pragma unroll
            for (int nt = 0; nt < 4; ++nt) {
                int key = nt * 16 + (lane & 15);
                bf16x8 bk = *(const bf16x8*)(Kl + key * 128 +
                                             ((d0 * 2) ^ ((key & 7) << 4)));
                sfr[nt] = __builtin_amdgcn_mfma_f32_16x16x32_bf16(
                              kk == 0 ? aq0 : aq1, bk, sfr[nt], 0, 0, 0);
            }
        }

        // ---- causal mask (only the diagonal tile can violate) ----
        if (t == dt) {
#pragma unroll
            for (int nt = 0; nt < 4; ++nt) {
                int keyg = t * 64 + nt * 16 + (lane & 15);
#pragma unroll
                for (int r = 0; r < 4; ++r) {
                    int qg = qt * 32 + wq * 16 + (lane >> 4) * 4 + r;
                    if (keyg > qg) sfr[nt][r] = -1e30f;
                }
            }
        }

        // ---- online softmax (rows live in 16-lane groups) ----
        float pf[4][4];
#pragma unroll
        for (int r = 0; r < 4; ++r) {
            float mx = fmaxf(fmaxf(sfr[0][r], sfr[1][r]), fmaxf(sfr[2][r], sfr[3][r]));
            mx = fmaxf(mx, __shfl_xor(mx, 1));
            mx = fmaxf(mx, __shfl_xor(mx, 2));
            mx = fmaxf(mx, __shfl_xor(mx, 4));
            mx = fmaxf(mx, __shfl_xor(mx, 8));
            float mn = fmaxf(m[r], mx);
            float scale = exp2f((m[r] - mn) * LOG2E);
            m[r] = mn;
            float rs = 0.0f;
#pragma unroll
            for (int nt = 0; nt < 4; ++nt) {
                float p = exp2f((sfr[nt][r] - mn) * LOG2E);
                pf[nt][r] = p;
                rs += p;
            }
            rs += __shfl_xor(rs, 1);
            rs += __shfl_xor(rs, 2);
            rs += __shfl_xor(rs, 4);
            rs += __shfl_xor(rs, 8);
            lsum[r] = lsum[r] * scale + rs;
#pragma unroll
            for (int nt = 0; nt < 4; ++nt) acc[nt][r] *= scale;
        }

        // ---- P -> LDS (bf16, swizzled), re-fragment for PV ----
#pragma unroll
        for (int nt = 0; nt < 4; ++nt) {
            int key = nt * 16 + (lane & 15);
#pragma unroll
            for (int r = 0; r < 4; ++r) {
                int q = (lane >> 4) * 4 + r;
                *(bf16_t*)((char*)&Plds[w][0] + q * 128 +
                           ((key * 2) ^ ((q & 7) << 4))) = (bf16_t)pf[nt][r];
            }
        }

        // ---- O += P V ---- (same-wave LDS dep; compiler inserts lgkmcnt)
#pragma unroll
        for (int kk = 0; kk < 2; ++kk) {
            int k0 = kk * 32 + (lane >> 4) * 8;
            int q  = lane & 15;
            bf16x8 ap = *(const bf16x8*)((char*)&Plds[w][0] + q * 128 +
                                         ((k0 * 2) ^ ((q & 7) << 4)));
#pragma unroll
            for (int nt = 0; nt < 4; ++nt) {
                int d = nt * 16 + (lane & 15);
                bf16x8 bv = *(const bf16x8*)(Vl + d * 128 +
                                             ((k0 * 2) ^ ((d & 7) << 4)));
                acc[nt] = __builtin_amdgcn_mfma_f32_16x16x32_bf16(ap, bv, acc[nt], 0, 0, 0);
            }
        }
    }

    // ---- flash-combine group 1 into group 0, normalize, store fp32 ----
    __syncthreads();
    float* Olds = (float*)&Klds[0][0];   // 32x64 fp32 = 8 KB
    float* Ml   = (float*)&Vlds[0][0];   // 32 floats
    float* Ll   = Ml + 32;
    if (g == 1) {
#pragma unroll
        for (int nt = 0; nt < 4; ++nt)
#pragma unroll
            for (int r = 0; r < 4; ++r)
                Olds[(wq * 16 + (lane >> 4) * 4 + r) * 64 + nt * 16 + (lane & 15)] = acc[nt][r];
        if ((lane & 15) == 0) {
#pragma unroll
            for (int r = 0; r < 4; ++r) {
                int rr = wq * 16 + (lane >> 4) * 4 + r;
                Ml[rr] = m[r];
                Ll[rr] = lsum[r];
            }
        }
    }
    __syncthreads();
    if (g == 0) {
        float* ob = out + ((size_t)batch * SS + qt * 32) * DOUT;
#pragma unroll
        for (int r = 0; r < 4; ++r) {
            int rr = wq * 16 + (lane >> 4) * 4 + r;
            float m1 = Ml[rr], l1 = Ll[rr];
            float mm = fmaxf(m[r], m1);
            float e0 = exp2f((m[r] - mm) * LOG2E);
            float e1 = exp2f((m1 - mm) * LOG2E);
            float li = 1.0f / (lsum[r] * e0 + l1 * e1);
#pragma unroll
            for (int nt = 0; nt < 4; ++nt) {
                int cc = nt * 16 + (lane & 15);
                ob[(size_t)rr * DOUT + cc] = (acc[nt][r] * e0 + Olds[rr * 64 + cc] * e1) * li;
            }
        }
    }
}

// ---------------------------------------------------------------------------
// Workspace layout (~6.4 MB):
//   [0, 2MB)   Kp bf16 [8][2048][64]
//   [2, 4MB)   Vp bf16
//   [4, 6MB)   Qp bf16 (pre-scaled by 1/8)
//   [6MB, +384KB) fw bf16 [3][65536] fragment-packed weights
// ---------------------------------------------------------------------------
extern "C" void kernel_launch(void* const* d_in, const int* in_sizes, int n_in,
                              void* d_out, int out_size, void* d_ws, size_t ws_size,
                              hipStream_t stream) {
    const float* Xk = (const float*)d_in[0];
    const float* Xv = (const float*)d_in[1];
    const float* Xq = (const float*)d_in[2];
    const float* Kw = (const float*)d_in[3];
    const float* Vw = (const float*)d_in[4];
    const float* Qw = (const float*)d_in[5];

    bf16_t* Kp = (bf16_t*)d_ws;
    bf16_t* Vp = Kp + (size_t)BB * SS * DOUT;
    bf16_t* Qp = Vp + (size_t)BB * SS * DOUT;
    bf16_t* fw = Qp + (size_t)BB * SS * DOUT;

    prep_weights<<<dim3(48), dim3(256), 0, stream>>>(Kw, Vw, Qw, fw);
    proj_kernel<<<dim3(256, 3), dim3(512), 0, stream>>>(Xk, Xv, Xq, fw, Kp, Vp, Qp);
    attn_kernel<<<dim3(64, 8), dim3(256), 0, stream>>>(Kp, Vp, Qp, (float*)d_out);
}